// Round 3
// baseline (50.162 us; speedup 1.0000x reference)
//
#include <hip/hip_runtime.h>
#include <math.h>

// Sizes (fixed by the problem)
#define Bb 8
#define Tt 32
#define Hh 64
#define Ww 64
#define Cc 3
#define Ff 24
#define Uu 128

typedef float v2f __attribute__((ext_vector_type(2)));

// Fast activations: |err| ~1e-6, threshold is 1.86e-4.
__device__ __forceinline__ float fast_sigmoid(float x) {
    float e = __builtin_amdgcn_exp2f(-1.442695040888963f * x);
    return __builtin_amdgcn_rcpf(1.f + e);
}
__device__ __forceinline__ float fast_tanh(float x) {
    float e = __builtin_amdgcn_exp2f(-2.885390081777927f * x);
    return 2.f * __builtin_amdgcn_rcpf(1.f + e) - 1.f;
}

// ---------------------------------------------------------------------------
// Kernel 1: fused per-frame stats + analytic double-conv + global-avg-pool.
// feat[frame][24] = mean_{h,w} conv2(conv1(x)) via 25 region stats/channel
// (linear convs + SAME padding collapse under the mean).
// ---------------------------------------------------------------------------
__global__ void convfeat_kernel(const float* __restrict__ x,
                                const float* __restrict__ w1, const float* __restrict__ b1,
                                const float* __restrict__ w2, const float* __restrict__ b2,
                                float* __restrict__ feat) {
    int n = blockIdx.x;                       // frame = b*T + t
    const float* xf = x + (size_t)n * (Hh * Ww * Cc);
    int tid  = threadIdx.x;                   // 0..255
    int row  = tid >> 2;
    int part = tid & 3;

    __shared__ float partial[256][3];
    __shared__ float rowsum[64][3];
    __shared__ float colv[64][12];
    __shared__ float st[75];                  // [c*25 + j]
    __shared__ float yst[24][9];

    float s0 = 0.f, s1 = 0.f, s2 = 0.f;
    const float4* p4 = (const float4*)(xf + (row * Ww + part * 16) * Cc);
#pragma unroll
    for (int i = 0; i < 12; ++i) {
        float4 v = p4[i];
        int j = i * 4;
        float vv[4] = {v.x, v.y, v.z, v.w};
#pragma unroll
        for (int l = 0; l < 4; ++l) {
            int c = (j + l) % 3;
            if (c == 0) s0 += vv[l]; else if (c == 1) s1 += vv[l]; else s2 += vv[l];
        }
    }
    partial[tid][0] = s0; partial[tid][1] = s1; partial[tid][2] = s2;

    if (tid < 64) {
        int r = tid;
#pragma unroll
        for (int w4 = 0; w4 < 4; ++w4) {
            int w = (w4 < 2) ? w4 : 60 + w4;
#pragma unroll
            for (int c = 0; c < 3; ++c) colv[r][w4 * 3 + c] = xf[(r * Ww + w) * Cc + c];
        }
    }
    __syncthreads();

    if (part == 0) {
#pragma unroll
        for (int c = 0; c < 3; ++c)
            rowsum[row][c] = partial[tid][c] + partial[tid + 1][c]
                           + partial[tid + 2][c] + partial[tid + 3][c];
    }
    __syncthreads();

    if (tid < 3) {
        float t = 0.f;
        for (int r = 0; r < 64; ++r) t += rowsum[r][tid];
        st[tid * 25 + 0] = t;
    }
    if (tid >= 4 && tid < 16) {
        int k = tid - 4; int ri = k / 3, c = k % 3;
        int r = (ri < 2) ? ri : 60 + ri;
        st[c * 25 + 1 + ri] = rowsum[r][c];
    }
    if (tid >= 64 && tid < 76) {
        int k = tid - 64;
        float t = 0.f;
        for (int r = 0; r < 64; ++r) t += colv[r][k];
        int wi = k / 3, c = k % 3;
        st[c * 25 + 5 + wi] = t;
    }
    if (tid >= 128 && tid < 176) {
        int k = tid - 128; int pos = k / 3, c = k % 3;
        int ri = pos >> 2, wi = pos & 3;
        int r = (ri < 2) ? ri : 60 + ri;
        int w = (wi < 2) ? wi : 60 + wi;
        st[c * 25 + 9 + pos] = xf[(r * Ww + w) * Cc + c];
    }
    __syncthreads();

    if (tid < 24) {
        int f = tid;
        float Sy = 0, r0 = 0, r63 = 0, c0 = 0, c63 = 0, y00 = 0, y0W = 0, yH0 = 0, yHW = 0;
        for (int c = 0; c < 3; ++c) {
            const float* S = st + c * 25;
            float Sx = S[0];
            float rX[4] = {S[1], S[2], S[3], S[4]};
            float cX[4] = {S[5], S[6], S[7], S[8]};
            const float* X = S + 9;
            #define W1(p, q) w1[(((p) * 3 + (q)) * 3 + c) * 24 + f]
#pragma unroll
            for (int p = 0; p < 3; ++p)
#pragma unroll
                for (int q = 0; q < 3; ++q) {
                    float t = Sx;
                    if (p == 0) t -= rX[3];
                    if (p == 2) t -= rX[0];
                    if (q == 0) t -= cX[3];
                    if (q == 2) t -= cX[0];
                    if (p == 0 && q == 0) t += X[3 * 4 + 3];
                    if (p == 0 && q == 2) t += X[3 * 4 + 0];
                    if (p == 2 && q == 0) t += X[0 * 4 + 3];
                    if (p == 2 && q == 2) t += X[0 * 4 + 0];
                    Sy += W1(p, q) * t;
                }
#pragma unroll
            for (int q = 0; q < 3; ++q) {
                float Rr0  = rX[0] - ((q == 0) ? X[0 * 4 + 3] : 0.f) - ((q == 2) ? X[0 * 4 + 0] : 0.f);
                float Rr1  = rX[1] - ((q == 0) ? X[1 * 4 + 3] : 0.f) - ((q == 2) ? X[1 * 4 + 0] : 0.f);
                float Rr62 = rX[2] - ((q == 0) ? X[2 * 4 + 3] : 0.f) - ((q == 2) ? X[2 * 4 + 0] : 0.f);
                float Rr63 = rX[3] - ((q == 0) ? X[3 * 4 + 3] : 0.f) - ((q == 2) ? X[3 * 4 + 0] : 0.f);
                r0  += W1(1, q) * Rr0  + W1(2, q) * Rr1;
                r63 += W1(0, q) * Rr62 + W1(1, q) * Rr63;
            }
#pragma unroll
            for (int p = 0; p < 3; ++p) {
                float Rc0  = cX[0] - ((p == 0) ? X[3 * 4 + 0] : 0.f) - ((p == 2) ? X[0 * 4 + 0] : 0.f);
                float Rc1  = cX[1] - ((p == 0) ? X[3 * 4 + 1] : 0.f) - ((p == 2) ? X[0 * 4 + 1] : 0.f);
                float Rc62 = cX[2] - ((p == 0) ? X[3 * 4 + 2] : 0.f) - ((p == 2) ? X[0 * 4 + 2] : 0.f);
                float Rc63 = cX[3] - ((p == 0) ? X[3 * 4 + 3] : 0.f) - ((p == 2) ? X[0 * 4 + 3] : 0.f);
                c0  += W1(p, 1) * Rc0  + W1(p, 2) * Rc1;
                c63 += W1(p, 0) * Rc62 + W1(p, 1) * Rc63;
            }
            y00 += W1(1, 1) * X[0 * 4 + 0] + W1(1, 2) * X[0 * 4 + 1]
                 + W1(2, 1) * X[1 * 4 + 0] + W1(2, 2) * X[1 * 4 + 1];
            y0W += W1(1, 0) * X[0 * 4 + 2] + W1(1, 1) * X[0 * 4 + 3]
                 + W1(2, 0) * X[1 * 4 + 2] + W1(2, 1) * X[1 * 4 + 3];
            yH0 += W1(0, 1) * X[2 * 4 + 0] + W1(0, 2) * X[2 * 4 + 1]
                 + W1(1, 1) * X[3 * 4 + 0] + W1(1, 2) * X[3 * 4 + 1];
            yHW += W1(0, 0) * X[2 * 4 + 2] + W1(0, 1) * X[2 * 4 + 3]
                 + W1(1, 0) * X[3 * 4 + 2] + W1(1, 1) * X[3 * 4 + 3];
            #undef W1
        }
        float bb = b1[f];
        yst[f][0] = Sy + 4096.f * bb;
        yst[f][1] = r0 + 64.f * bb;
        yst[f][2] = r63 + 64.f * bb;
        yst[f][3] = c0 + 64.f * bb;
        yst[f][4] = c63 + 64.f * bb;
        yst[f][5] = y00 + bb; yst[f][6] = y0W + bb;
        yst[f][7] = yH0 + bb; yst[f][8] = yHW + bb;
    }
    __syncthreads();

    if (tid < 24) {
        int g = tid;
        float acc = 0.f;
        for (int f = 0; f < 24; ++f) {
            float Sy = yst[f][0], rY0 = yst[f][1], rY63 = yst[f][2], cY0 = yst[f][3], cY63 = yst[f][4];
            float yc00 = yst[f][5], yc0W = yst[f][6], ycH0 = yst[f][7], ycHW = yst[f][8];
#pragma unroll
            for (int p = 0; p < 3; ++p)
#pragma unroll
                for (int q = 0; q < 3; ++q) {
                    float t = Sy;
                    if (p == 0) t -= rY63;
                    if (p == 2) t -= rY0;
                    if (q == 0) t -= cY63;
                    if (q == 2) t -= cY0;
                    if (p == 0 && q == 0) t += ycHW;
                    if (p == 0 && q == 2) t += ycH0;
                    if (p == 2 && q == 0) t += yc0W;
                    if (p == 2 && q == 2) t += yc00;
                    acc += w2[(((p * 3 + q) * 24 + f) * 24) + g] * t;
                }
        }
        feat[(size_t)n * 24 + g] = b2[g] + acc * (1.f / 4096.f);
    }
}

// ---------------------------------------------------------------------------
// Kernel 2: fused gate-preactivation + LSTM recurrence + output projection.
// One block per batch element, 512 threads.
// Thread (up = tid&63, q = (tid>>6)&3, s = tid>>8):
//   phase A: packed dual-FP32 dots for unit-pair (2up,2up+1), gates {2s,2s+1},
//            h-chunk [32q,32q+32); plus this thread's input-projection gx for
//            column (g'=2s+(q&1), u'=2up+(q>>1)), folded into the partial.
//   phase B (tid<128): sum 4 chunk-partials per gate, fast activations,
//            c/h update, h history to LDS.
// 2 barriers per step.
// ---------------------------------------------------------------------------
__global__ __launch_bounds__(512, 1) void lstm_kernel(
        const float* __restrict__ feat,
        const float* __restrict__ Wf, const float* __restrict__ bf,
        const float* __restrict__ Wi, const float* __restrict__ bi,
        const float* __restrict__ Wc, const float* __restrict__ bc,
        const float* __restrict__ Wo, const float* __restrict__ bo,
        const float* __restrict__ out_w, const float* __restrict__ out_b,
        float* __restrict__ out) {
    int b   = blockIdx.x;
    int tid = threadIdx.x;
    int up  = tid & 63;
    int q   = (tid >> 6) & 3;                 // wave-uniform
    int s   = tid >> 8;                       // wave-uniform

    const float* Wg0 = (s == 0) ? Wf : Wc;    // gate 2s
    const float* Wg1 = (s == 0) ? Wi : Wo;    // gate 2s+1

    // Recurrent weights: rows 24+32q..+32, unit-pair columns (contiguous b64).
    v2f w0[32], w1[32];
#pragma unroll
    for (int r = 0; r < 32; ++r) {
        w0[r] = *(const v2f*)(Wg0 + (size_t)(Ff + 32 * q + r) * Uu + 2 * up);
        w1[r] = *(const v2f*)(Wg1 + (size_t)(Ff + 32 * q + r) * Uu + 2 * up);
    }

    // Input-projection column for this thread: g' = 2s+(q&1), u' = 2up+(q>>1).
    const float* Wgx = (q & 1) ? Wg1 : Wg0;
    const float* bgx = (s == 0) ? ((q & 1) ? bi : bf) : ((q & 1) ? bo : bc);
    int ucol = 2 * up + ((q >> 1) & 1);
    float w24[Ff];
#pragma unroll
    for (int k = 0; k < Ff; ++k) w24[k] = Wgx[(size_t)k * Uu + ucol];
    float biasv = bgx[ucol];

    __shared__ float hs[Uu];
    __shared__ float part[16][Uu];            // [q*4+g][u] (written as v2f pairs)
    __shared__ float hist[Tt][Uu];

    float cs = 0.f;
    if (tid < Uu) hs[tid] = 0.f;
    __syncthreads();

    const float* ftb = feat + (size_t)(b * Tt) * Ff;

    for (int t = 0; t < Tt; ++t) {
        // gx: input projection (feat uniform -> scalar loads), bias included.
        float gxv = biasv;
        const float* ft = ftb + t * Ff;
#pragma unroll
        for (int k = 0; k < Ff; ++k) gxv = fmaf(ft[k], w24[k], gxv);

        // phase A: 64 packed FMAs (2 gates x 32 rows, 2 units each).
        v2f acc0 = {0.f, 0.f}, acc1 = {0.f, 0.f};
        const v2f* hp = (const v2f*)(hs + q * 32);
#pragma unroll
        for (int j = 0; j < 16; ++j) {
            v2f h2 = hp[j];
            // row 2j: splat h2.lo into both lanes (op_sel_hi[1]=0).
            asm("v_pk_fma_f32 %0, %2, %3, %0 op_sel:[0,0,0] op_sel_hi:[1,0,1]\n\t"
                "v_pk_fma_f32 %1, %4, %3, %1 op_sel:[0,0,0] op_sel_hi:[1,0,1]"
                : "+v"(acc0), "+v"(acc1)
                : "v"(w0[2 * j]), "v"(h2), "v"(w1[2 * j]));
            // row 2j+1: splat h2.hi into both lanes (op_sel[1]=1).
            asm("v_pk_fma_f32 %0, %2, %3, %0 op_sel:[0,1,0] op_sel_hi:[1,1,1]\n\t"
                "v_pk_fma_f32 %1, %4, %3, %1 op_sel:[0,1,0] op_sel_hi:[1,1,1]"
                : "+v"(acc0), "+v"(acc1)
                : "v"(w0[2 * j + 1]), "v"(h2), "v"(w1[2 * j + 1]));
        }

        // Fold gx into the matching partial component (wave-uniform branch).
        if ((q & 1) == 0) { if (q & 2) acc0.y += gxv; else acc0.x += gxv; }
        else              { if (q & 2) acc1.y += gxv; else acc1.x += gxv; }

        v2f* pb = (v2f*)part;
        pb[(q * 4 + 2 * s + 0) * 64 + up] = acc0;
        pb[(q * 4 + 2 * s + 1) * 64 + up] = acc1;
        __syncthreads();

        // phase B: state update on 128 threads.
        if (tid < Uu) {
            int u = tid;
            float sf = part[0][u]  + part[4][u]  + part[8][u]  + part[12][u];
            float si = part[1][u]  + part[5][u]  + part[9][u]  + part[13][u];
            float sg = part[2][u]  + part[6][u]  + part[10][u] + part[14][u];
            float so = part[3][u]  + part[7][u]  + part[11][u] + part[15][u];
            float f = fast_sigmoid(sf);
            float i = fast_sigmoid(si);
            float g = fast_tanh(sg);
            float o = fast_sigmoid(so);
            cs = cs * f + i * g;
            float hn = fast_tanh(cs) * o;
            hs[u] = hn;
            hist[t][u] = hn;
        }
        __syncthreads();
    }

    // Epilogue: out[b][t] = hist[t] . out_w + out_b, 16 threads per t.
    int tt = tid >> 4, j = tid & 15;
    const float4* hh = (const float4*)(&hist[tt][j * 8]);
    float4 a0 = hh[0], a1 = hh[1];
    const float* owp = out_w + j * 8;
    float pw = a0.x * owp[0] + a0.y * owp[1] + a0.z * owp[2] + a0.w * owp[3]
             + a1.x * owp[4] + a1.y * owp[5] + a1.z * owp[6] + a1.w * owp[7];
#pragma unroll
    for (int off = 8; off > 0; off >>= 1) pw += __shfl_down(pw, off, 16);
    if (j == 0) out[b * Tt + tt] = pw + out_b[0];
}

// ---------------------------------------------------------------------------
extern "C" void kernel_launch(void* const* d_in, const int* in_sizes, int n_in,
                              void* d_out, int out_size, void* d_ws, size_t ws_size,
                              hipStream_t stream) {
    const float* x   = (const float*)d_in[0];
    const float* w1  = (const float*)d_in[1];
    const float* b1  = (const float*)d_in[2];
    const float* w2  = (const float*)d_in[3];
    const float* b2  = (const float*)d_in[4];
    const float* Wf  = (const float*)d_in[5];
    const float* bf  = (const float*)d_in[6];
    const float* Wi  = (const float*)d_in[7];
    const float* bi  = (const float*)d_in[8];
    const float* Wc  = (const float*)d_in[9];
    const float* bc  = (const float*)d_in[10];
    const float* Wo  = (const float*)d_in[11];
    const float* bo  = (const float*)d_in[12];
    const float* ow  = (const float*)d_in[13];
    const float* ob  = (const float*)d_in[14];
    float* out = (float*)d_out;

    float* feat = (float*)d_ws;               // 256*24 = 6144 floats

    convfeat_kernel<<<Bb * Tt, 256, 0, stream>>>(x, w1, b1, w2, b2, feat);
    lstm_kernel<<<Bb, 512, 0, stream>>>(feat, Wf, bf, Wi, bi, Wc, bc, Wo, bo,
                                        ow, ob, out);
}

// Round 4
// 45.486 us; speedup vs baseline: 1.1028x; 1.1028x over previous
//
#include <hip/hip_runtime.h>
#include <math.h>

// Sizes (fixed by the problem)
#define Bb 8
#define Tt 32
#define Hh 64
#define Ww 64
#define Cc 3
#define Ff 24
#define Uu 128

typedef float v2f __attribute__((ext_vector_type(2)));

// Fast activations: |err| ~1e-6, threshold is 1.86e-4.
__device__ __forceinline__ float fast_sigmoid(float x) {
    float e = __builtin_amdgcn_exp2f(-1.442695040888963f * x);
    return __builtin_amdgcn_rcpf(1.f + e);
}
__device__ __forceinline__ float fast_tanh(float x) {
    float e = __builtin_amdgcn_exp2f(-2.885390081777927f * x);
    return 2.f * __builtin_amdgcn_rcpf(1.f + e) - 1.f;
}

// ---------------------------------------------------------------------------
// Kernel 1: fused per-frame stats + analytic double-conv + global-avg-pool.
// feat[frame][24] = mean_{h,w} conv2(conv1(x)) via 25 region stats/channel
// (linear convs + SAME padding collapse under the mean).
// ---------------------------------------------------------------------------
__global__ void convfeat_kernel(const float* __restrict__ x,
                                const float* __restrict__ w1, const float* __restrict__ b1,
                                const float* __restrict__ w2, const float* __restrict__ b2,
                                float* __restrict__ feat) {
    int n = blockIdx.x;                       // frame = b*T + t
    const float* xf = x + (size_t)n * (Hh * Ww * Cc);
    int tid  = threadIdx.x;                   // 0..255
    int row  = tid >> 2;
    int part = tid & 3;

    __shared__ float partial[256][3];
    __shared__ float rowsum[64][3];
    __shared__ float colv[64][12];
    __shared__ float st[75];                  // [c*25 + j]
    __shared__ float yst[24][9];

    float s0 = 0.f, s1 = 0.f, s2 = 0.f;
    const float4* p4 = (const float4*)(xf + (row * Ww + part * 16) * Cc);
#pragma unroll
    for (int i = 0; i < 12; ++i) {
        float4 v = p4[i];
        int j = i * 4;
        float vv[4] = {v.x, v.y, v.z, v.w};
#pragma unroll
        for (int l = 0; l < 4; ++l) {
            int c = (j + l) % 3;
            if (c == 0) s0 += vv[l]; else if (c == 1) s1 += vv[l]; else s2 += vv[l];
        }
    }
    partial[tid][0] = s0; partial[tid][1] = s1; partial[tid][2] = s2;

    if (tid < 64) {
        int r = tid;
#pragma unroll
        for (int w4 = 0; w4 < 4; ++w4) {
            int w = (w4 < 2) ? w4 : 60 + w4;
#pragma unroll
            for (int c = 0; c < 3; ++c) colv[r][w4 * 3 + c] = xf[(r * Ww + w) * Cc + c];
        }
    }
    __syncthreads();

    if (part == 0) {
#pragma unroll
        for (int c = 0; c < 3; ++c)
            rowsum[row][c] = partial[tid][c] + partial[tid + 1][c]
                           + partial[tid + 2][c] + partial[tid + 3][c];
    }
    __syncthreads();

    if (tid < 3) {
        float t = 0.f;
        for (int r = 0; r < 64; ++r) t += rowsum[r][tid];
        st[tid * 25 + 0] = t;
    }
    if (tid >= 4 && tid < 16) {
        int k = tid - 4; int ri = k / 3, c = k % 3;
        int r = (ri < 2) ? ri : 60 + ri;
        st[c * 25 + 1 + ri] = rowsum[r][c];
    }
    if (tid >= 64 && tid < 76) {
        int k = tid - 64;
        float t = 0.f;
        for (int r = 0; r < 64; ++r) t += colv[r][k];
        int wi = k / 3, c = k % 3;
        st[c * 25 + 5 + wi] = t;
    }
    if (tid >= 128 && tid < 176) {
        int k = tid - 128; int pos = k / 3, c = k % 3;
        int ri = pos >> 2, wi = pos & 3;
        int r = (ri < 2) ? ri : 60 + ri;
        int w = (wi < 2) ? wi : 60 + wi;
        st[c * 25 + 9 + pos] = xf[(r * Ww + w) * Cc + c];
    }
    __syncthreads();

    if (tid < 24) {
        int f = tid;
        float Sy = 0, r0 = 0, r63 = 0, c0 = 0, c63 = 0, y00 = 0, y0W = 0, yH0 = 0, yHW = 0;
        for (int c = 0; c < 3; ++c) {
            const float* S = st + c * 25;
            float Sx = S[0];
            float rX[4] = {S[1], S[2], S[3], S[4]};
            float cX[4] = {S[5], S[6], S[7], S[8]};
            const float* X = S + 9;
            #define W1(p, q) w1[(((p) * 3 + (q)) * 3 + c) * 24 + f]
#pragma unroll
            for (int p = 0; p < 3; ++p)
#pragma unroll
                for (int q = 0; q < 3; ++q) {
                    float t = Sx;
                    if (p == 0) t -= rX[3];
                    if (p == 2) t -= rX[0];
                    if (q == 0) t -= cX[3];
                    if (q == 2) t -= cX[0];
                    if (p == 0 && q == 0) t += X[3 * 4 + 3];
                    if (p == 0 && q == 2) t += X[3 * 4 + 0];
                    if (p == 2 && q == 0) t += X[0 * 4 + 3];
                    if (p == 2 && q == 2) t += X[0 * 4 + 0];
                    Sy += W1(p, q) * t;
                }
#pragma unroll
            for (int q = 0; q < 3; ++q) {
                float Rr0  = rX[0] - ((q == 0) ? X[0 * 4 + 3] : 0.f) - ((q == 2) ? X[0 * 4 + 0] : 0.f);
                float Rr1  = rX[1] - ((q == 0) ? X[1 * 4 + 3] : 0.f) - ((q == 2) ? X[1 * 4 + 0] : 0.f);
                float Rr62 = rX[2] - ((q == 0) ? X[2 * 4 + 3] : 0.f) - ((q == 2) ? X[2 * 4 + 0] : 0.f);
                float Rr63 = rX[3] - ((q == 0) ? X[3 * 4 + 3] : 0.f) - ((q == 2) ? X[3 * 4 + 0] : 0.f);
                r0  += W1(1, q) * Rr0  + W1(2, q) * Rr1;
                r63 += W1(0, q) * Rr62 + W1(1, q) * Rr63;
            }
#pragma unroll
            for (int p = 0; p < 3; ++p) {
                float Rc0  = cX[0] - ((p == 0) ? X[3 * 4 + 0] : 0.f) - ((p == 2) ? X[0 * 4 + 0] : 0.f);
                float Rc1  = cX[1] - ((p == 0) ? X[3 * 4 + 1] : 0.f) - ((p == 2) ? X[0 * 4 + 1] : 0.f);
                float Rc62 = cX[2] - ((p == 0) ? X[3 * 4 + 2] : 0.f) - ((p == 2) ? X[0 * 4 + 2] : 0.f);
                float Rc63 = cX[3] - ((p == 0) ? X[3 * 4 + 3] : 0.f) - ((p == 2) ? X[0 * 4 + 3] : 0.f);
                c0  += W1(p, 1) * Rc0  + W1(p, 2) * Rc1;
                c63 += W1(p, 0) * Rc62 + W1(p, 1) * Rc63;
            }
            y00 += W1(1, 1) * X[0 * 4 + 0] + W1(1, 2) * X[0 * 4 + 1]
                 + W1(2, 1) * X[1 * 4 + 0] + W1(2, 2) * X[1 * 4 + 1];
            y0W += W1(1, 0) * X[0 * 4 + 2] + W1(1, 1) * X[0 * 4 + 3]
                 + W1(2, 0) * X[1 * 4 + 2] + W1(2, 1) * X[1 * 4 + 3];
            yH0 += W1(0, 1) * X[2 * 4 + 0] + W1(0, 2) * X[2 * 4 + 1]
                 + W1(1, 1) * X[3 * 4 + 0] + W1(1, 2) * X[3 * 4 + 1];
            yHW += W1(0, 0) * X[2 * 4 + 2] + W1(0, 1) * X[2 * 4 + 3]
                 + W1(1, 0) * X[3 * 4 + 2] + W1(1, 1) * X[3 * 4 + 3];
            #undef W1
        }
        float bb = b1[f];
        yst[f][0] = Sy + 4096.f * bb;
        yst[f][1] = r0 + 64.f * bb;
        yst[f][2] = r63 + 64.f * bb;
        yst[f][3] = c0 + 64.f * bb;
        yst[f][4] = c63 + 64.f * bb;
        yst[f][5] = y00 + bb; yst[f][6] = y0W + bb;
        yst[f][7] = yH0 + bb; yst[f][8] = yHW + bb;
    }
    __syncthreads();

    if (tid < 24) {
        int g = tid;
        float acc = 0.f;
        for (int f = 0; f < 24; ++f) {
            float Sy = yst[f][0], rY0 = yst[f][1], rY63 = yst[f][2], cY0 = yst[f][3], cY63 = yst[f][4];
            float yc00 = yst[f][5], yc0W = yst[f][6], ycH0 = yst[f][7], ycHW = yst[f][8];
#pragma unroll
            for (int p = 0; p < 3; ++p)
#pragma unroll
                for (int q = 0; q < 3; ++q) {
                    float t = Sy;
                    if (p == 0) t -= rY63;
                    if (p == 2) t -= rY0;
                    if (q == 0) t -= cY63;
                    if (q == 2) t -= cY0;
                    if (p == 0 && q == 0) t += ycHW;
                    if (p == 0 && q == 2) t += ycH0;
                    if (p == 2 && q == 0) t += yc0W;
                    if (p == 2 && q == 2) t += yc00;
                    acc += w2[(((p * 3 + q) * 24 + f) * 24) + g] * t;
                }
        }
        feat[(size_t)n * 24 + g] = b2[g] + acc * (1.f / 4096.f);
    }
}

// ---------------------------------------------------------------------------
// Kernel 2: input-part of gate preactivations (embarrassingly parallel).
// G[(t*8+b)*512 + g*128 + u] = bias_g[u] + feat[b*T+t, :24] @ W_g[0:24, u]
// ---------------------------------------------------------------------------
__global__ void gpre_kernel(const float* __restrict__ feat,
                            const float* __restrict__ Wf, const float* __restrict__ bf,
                            const float* __restrict__ Wi, const float* __restrict__ bi,
                            const float* __restrict__ Wc, const float* __restrict__ bc,
                            const float* __restrict__ Wo, const float* __restrict__ bo,
                            float* __restrict__ G) {
    int blk = blockIdx.x;                     // t*8 + b
    int t = blk >> 3, b = blk & 7;
    int tid = threadIdx.x;                    // g*128 + u
    int g = tid >> 7, u = tid & 127;
    const float* W    = (g == 0) ? Wf : (g == 1) ? Wi : (g == 2) ? Wc : Wo;
    const float* bias = (g == 0) ? bf : (g == 1) ? bi : (g == 2) ? bc : bo;
    int n = b * Tt + t;
    float acc = bias[u];
#pragma unroll
    for (int k = 0; k < Ff; ++k) acc += feat[(size_t)n * Ff + k] * W[k * Uu + u];
    G[(size_t)blk * 512 + tid] = acc;
}

// ---------------------------------------------------------------------------
// Kernel 3: LSTM recurrence. One block per batch element, 1024 threads.
// 1024-thread workgroup forces 4 waves/SIMD residency => hard 128-VGPR cap;
// per-thread weight state is 64 VGPRs (32 x v2f) so it MUST stay in registers
// (rounds 1-3 all lost to the compiler sinking/spilling larger arrays).
// Thread (up = tid&63, g = (tid>>6)&3, q = tid>>8):
//   phase A: acc(v2f) = sum_{r<32} W_g[24+32q+r][2up..2up+1] * h[32q+r]
//            (h via broadcast ds_read_b64 + pk_fma op_sel splat)
//   phase B (tid<128): sum 4 chunk partials/gate + G, activations, c/h update.
// 2 barriers per step.
// ---------------------------------------------------------------------------
__global__ __launch_bounds__(1024, 1) void lstm_kernel(
        const float* __restrict__ G,
        const float* __restrict__ Wf, const float* __restrict__ Wi,
        const float* __restrict__ Wc, const float* __restrict__ Wo,
        const float* __restrict__ out_w, const float* __restrict__ out_b,
        float* __restrict__ out) {
    int b   = blockIdx.x;
    int tid = threadIdx.x;
    int up  = tid & 63;                       // unit pair
    int g   = (tid >> 6) & 3;                 // gate (wave-uniform)
    int q   = tid >> 8;                       // row chunk (wave-uniform)
    const float* Wg = (g == 0) ? Wf : (g == 1) ? Wi : (g == 2) ? Wc : Wo;

    // 32 v2f = 64 VGPRs of recurrent weights: rows 24+32q..+32, cols (2up,2up+1).
    v2f w[32];
#pragma unroll
    for (int r = 0; r < 32; ++r)
        w[r] = *(const v2f*)(Wg + (size_t)(Ff + 32 * q + r) * Uu + 2 * up);

    __shared__ float hs[Uu];
    __shared__ float part[16][Uu];            // [q*4+g][u]
    __shared__ float hist[Tt][Uu];

    float cs = 0.f;
    if (tid < Uu) hs[tid] = 0.f;
    __syncthreads();

    for (int t = 0; t < Tt; ++t) {
        // Prefetch this step's input-projection values (used in phase B).
        float g0 = 0.f, g1 = 0.f, g2 = 0.f, g3 = 0.f;
        if (tid < Uu) {
            const float* Gt = G + ((size_t)(t * Bb + b)) * 512 + tid;
            g0 = Gt[0]; g1 = Gt[128]; g2 = Gt[256]; g3 = Gt[384];
        }

        // phase A: 16 broadcast ds_read_b64 + 32 pk_fma (2 indep chains).
        v2f ae = {0.f, 0.f}, ao = {0.f, 0.f};
        const v2f* hp = (const v2f*)(hs + q * 32);
#pragma unroll
        for (int j = 0; j < 16; ++j) {
            v2f h2 = hp[j];
            asm("v_pk_fma_f32 %0, %1, %2, %0 op_sel:[0,0,0] op_sel_hi:[1,0,1]"
                : "+v"(ae) : "v"(w[2 * j]), "v"(h2));
            asm("v_pk_fma_f32 %0, %1, %2, %0 op_sel:[0,1,0] op_sel_hi:[1,1,1]"
                : "+v"(ao) : "v"(w[2 * j + 1]), "v"(h2));
        }
        v2f acc = ae + ao;
        *(v2f*)&part[q * 4 + g][2 * up] = acc;
        __syncthreads();

        // phase B: state update on 128 threads.
        if (tid < Uu) {
            int u = tid;
            float sf = part[0][u] + part[4][u] + part[8][u]  + part[12][u] + g0;
            float si = part[1][u] + part[5][u] + part[9][u]  + part[13][u] + g1;
            float sg = part[2][u] + part[6][u] + part[10][u] + part[14][u] + g2;
            float so = part[3][u] + part[7][u] + part[11][u] + part[15][u] + g3;
            float f  = fast_sigmoid(sf);
            float i  = fast_sigmoid(si);
            float gg = fast_tanh(sg);
            float o  = fast_sigmoid(so);
            cs = cs * f + i * gg;
            float hn = fast_tanh(cs) * o;
            hs[u] = hn;
            hist[t][u] = hn;
        }
        __syncthreads();
    }

    // Epilogue: out[b][t] = hist[t] . out_w + out_b, 32 threads per t.
    int tt = tid >> 5, j = tid & 31;
    const float4* hh = (const float4*)(&hist[tt][j * 4]);
    float4 a0 = hh[0];
    const float* owp = out_w + j * 4;
    float pw = a0.x * owp[0] + a0.y * owp[1] + a0.z * owp[2] + a0.w * owp[3];
#pragma unroll
    for (int off = 16; off > 0; off >>= 1) pw += __shfl_down(pw, off, 32);
    if (j == 0) out[b * Tt + tt] = pw + out_b[0];
}

// ---------------------------------------------------------------------------
extern "C" void kernel_launch(void* const* d_in, const int* in_sizes, int n_in,
                              void* d_out, int out_size, void* d_ws, size_t ws_size,
                              hipStream_t stream) {
    const float* x   = (const float*)d_in[0];
    const float* w1  = (const float*)d_in[1];
    const float* b1  = (const float*)d_in[2];
    const float* w2  = (const float*)d_in[3];
    const float* b2  = (const float*)d_in[4];
    const float* Wf  = (const float*)d_in[5];
    const float* bf  = (const float*)d_in[6];
    const float* Wi  = (const float*)d_in[7];
    const float* bi  = (const float*)d_in[8];
    const float* Wc  = (const float*)d_in[9];
    const float* bc  = (const float*)d_in[10];
    const float* Wo  = (const float*)d_in[11];
    const float* bo  = (const float*)d_in[12];
    const float* ow  = (const float*)d_in[13];
    const float* ob  = (const float*)d_in[14];
    float* out = (float*)d_out;

    float* ws   = (float*)d_ws;
    float* feat = ws;                         // 256*24  = 6144 floats
    float* G    = ws + 6144;                  // 256*512 = 131072 floats

    convfeat_kernel<<<Bb * Tt, 256, 0, stream>>>(x, w1, b1, w2, b2, feat);
    gpre_kernel<<<Bb * Tt, 512, 0, stream>>>(feat, Wf, bf, Wi, bi, Wc, bc, Wo, bo, G);
    lstm_kernel<<<Bb, 1024, 0, stream>>>(G, Wf, Wi, Wc, Wo, ow, ob, out);
}

// Round 5
// 45.397 us; speedup vs baseline: 1.1050x; 1.0020x over previous
//
#include <hip/hip_runtime.h>
#include <math.h>

// Sizes (fixed by the problem)
#define Bb 8
#define Tt 32
#define Hh 64
#define Ww 64
#define Cc 3
#define Ff 24
#define Uu 128

typedef float v2f __attribute__((ext_vector_type(2)));

// Fast activations: |err| ~1e-6, threshold is 1.86e-4.
__device__ __forceinline__ float fast_sigmoid(float x) {
    float e = __builtin_amdgcn_exp2f(-1.442695040888963f * x);
    return __builtin_amdgcn_rcpf(1.f + e);
}
__device__ __forceinline__ float fast_tanh(float x) {
    float e = __builtin_amdgcn_exp2f(-2.885390081777927f * x);
    return 2.f * __builtin_amdgcn_rcpf(1.f + e) - 1.f;
}

// ---------------------------------------------------------------------------
// Kernel 1: fused per-frame stats + analytic double-conv + global-avg-pool.
// feat[frame][24] = mean_{h,w} conv2(conv1(x)) via 25 region stats/channel
// (linear convs + SAME padding collapse under the mean).
// ---------------------------------------------------------------------------
__global__ void convfeat_kernel(const float* __restrict__ x,
                                const float* __restrict__ w1, const float* __restrict__ b1,
                                const float* __restrict__ w2, const float* __restrict__ b2,
                                float* __restrict__ feat) {
    int n = blockIdx.x;                       // frame = b*T + t
    const float* xf = x + (size_t)n * (Hh * Ww * Cc);
    int tid  = threadIdx.x;                   // 0..255
    int row  = tid >> 2;
    int part = tid & 3;

    __shared__ float partial[256][3];
    __shared__ float rowsum[64][3];
    __shared__ float colv[64][12];
    __shared__ float st[75];                  // [c*25 + j]
    __shared__ float yst[24][9];

    float s0 = 0.f, s1 = 0.f, s2 = 0.f;
    const float4* p4 = (const float4*)(xf + (row * Ww + part * 16) * Cc);
#pragma unroll
    for (int i = 0; i < 12; ++i) {
        float4 v = p4[i];
        int j = i * 4;
        float vv[4] = {v.x, v.y, v.z, v.w};
#pragma unroll
        for (int l = 0; l < 4; ++l) {
            int c = (j + l) % 3;
            if (c == 0) s0 += vv[l]; else if (c == 1) s1 += vv[l]; else s2 += vv[l];
        }
    }
    partial[tid][0] = s0; partial[tid][1] = s1; partial[tid][2] = s2;

    if (tid < 64) {
        int r = tid;
#pragma unroll
        for (int w4 = 0; w4 < 4; ++w4) {
            int w = (w4 < 2) ? w4 : 60 + w4;
#pragma unroll
            for (int c = 0; c < 3; ++c) colv[r][w4 * 3 + c] = xf[(r * Ww + w) * Cc + c];
        }
    }
    __syncthreads();

    if (part == 0) {
#pragma unroll
        for (int c = 0; c < 3; ++c)
            rowsum[row][c] = partial[tid][c] + partial[tid + 1][c]
                           + partial[tid + 2][c] + partial[tid + 3][c];
    }
    __syncthreads();

    if (tid < 3) {
        float t = 0.f;
        for (int r = 0; r < 64; ++r) t += rowsum[r][tid];
        st[tid * 25 + 0] = t;
    }
    if (tid >= 4 && tid < 16) {
        int k = tid - 4; int ri = k / 3, c = k % 3;
        int r = (ri < 2) ? ri : 60 + ri;
        st[c * 25 + 1 + ri] = rowsum[r][c];
    }
    if (tid >= 64 && tid < 76) {
        int k = tid - 64;
        float t = 0.f;
        for (int r = 0; r < 64; ++r) t += colv[r][k];
        int wi = k / 3, c = k % 3;
        st[c * 25 + 5 + wi] = t;
    }
    if (tid >= 128 && tid < 176) {
        int k = tid - 128; int pos = k / 3, c = k % 3;
        int ri = pos >> 2, wi = pos & 3;
        int r = (ri < 2) ? ri : 60 + ri;
        int w = (wi < 2) ? wi : 60 + wi;
        st[c * 25 + 9 + pos] = xf[(r * Ww + w) * Cc + c];
    }
    __syncthreads();

    if (tid < 24) {
        int f = tid;
        float Sy = 0, r0 = 0, r63 = 0, c0 = 0, c63 = 0, y00 = 0, y0W = 0, yH0 = 0, yHW = 0;
        for (int c = 0; c < 3; ++c) {
            const float* S = st + c * 25;
            float Sx = S[0];
            float rX[4] = {S[1], S[2], S[3], S[4]};
            float cX[4] = {S[5], S[6], S[7], S[8]};
            const float* X = S + 9;
            #define W1(p, q) w1[(((p) * 3 + (q)) * 3 + c) * 24 + f]
#pragma unroll
            for (int p = 0; p < 3; ++p)
#pragma unroll
                for (int q = 0; q < 3; ++q) {
                    float t = Sx;
                    if (p == 0) t -= rX[3];
                    if (p == 2) t -= rX[0];
                    if (q == 0) t -= cX[3];
                    if (q == 2) t -= cX[0];
                    if (p == 0 && q == 0) t += X[3 * 4 + 3];
                    if (p == 0 && q == 2) t += X[3 * 4 + 0];
                    if (p == 2 && q == 0) t += X[0 * 4 + 3];
                    if (p == 2 && q == 2) t += X[0 * 4 + 0];
                    Sy += W1(p, q) * t;
                }
#pragma unroll
            for (int q = 0; q < 3; ++q) {
                float Rr0  = rX[0] - ((q == 0) ? X[0 * 4 + 3] : 0.f) - ((q == 2) ? X[0 * 4 + 0] : 0.f);
                float Rr1  = rX[1] - ((q == 0) ? X[1 * 4 + 3] : 0.f) - ((q == 2) ? X[1 * 4 + 0] : 0.f);
                float Rr62 = rX[2] - ((q == 0) ? X[2 * 4 + 3] : 0.f) - ((q == 2) ? X[2 * 4 + 0] : 0.f);
                float Rr63 = rX[3] - ((q == 0) ? X[3 * 4 + 3] : 0.f) - ((q == 2) ? X[3 * 4 + 0] : 0.f);
                r0  += W1(1, q) * Rr0  + W1(2, q) * Rr1;
                r63 += W1(0, q) * Rr62 + W1(1, q) * Rr63;
            }
#pragma unroll
            for (int p = 0; p < 3; ++p) {
                float Rc0  = cX[0] - ((p == 0) ? X[3 * 4 + 0] : 0.f) - ((p == 2) ? X[0 * 4 + 0] : 0.f);
                float Rc1  = cX[1] - ((p == 0) ? X[3 * 4 + 1] : 0.f) - ((p == 2) ? X[0 * 4 + 1] : 0.f);
                float Rc62 = cX[2] - ((p == 0) ? X[3 * 4 + 2] : 0.f) - ((p == 2) ? X[0 * 4 + 2] : 0.f);
                float Rc63 = cX[3] - ((p == 0) ? X[3 * 4 + 3] : 0.f) - ((p == 2) ? X[0 * 4 + 3] : 0.f);
                c0  += W1(p, 1) * Rc0  + W1(p, 2) * Rc1;
                c63 += W1(p, 0) * Rc62 + W1(p, 1) * Rc63;
            }
            y00 += W1(1, 1) * X[0 * 4 + 0] + W1(1, 2) * X[0 * 4 + 1]
                 + W1(2, 1) * X[1 * 4 + 0] + W1(2, 2) * X[1 * 4 + 1];
            y0W += W1(1, 0) * X[0 * 4 + 2] + W1(1, 1) * X[0 * 4 + 3]
                 + W1(2, 0) * X[1 * 4 + 2] + W1(2, 1) * X[1 * 4 + 3];
            yH0 += W1(0, 1) * X[2 * 4 + 0] + W1(0, 2) * X[2 * 4 + 1]
                 + W1(1, 1) * X[3 * 4 + 0] + W1(1, 2) * X[3 * 4 + 1];
            yHW += W1(0, 0) * X[2 * 4 + 2] + W1(0, 1) * X[2 * 4 + 3]
                 + W1(1, 0) * X[3 * 4 + 2] + W1(1, 1) * X[3 * 4 + 3];
            #undef W1
        }
        float bb = b1[f];
        yst[f][0] = Sy + 4096.f * bb;
        yst[f][1] = r0 + 64.f * bb;
        yst[f][2] = r63 + 64.f * bb;
        yst[f][3] = c0 + 64.f * bb;
        yst[f][4] = c63 + 64.f * bb;
        yst[f][5] = y00 + bb; yst[f][6] = y0W + bb;
        yst[f][7] = yH0 + bb; yst[f][8] = yHW + bb;
    }
    __syncthreads();

    if (tid < 24) {
        int g = tid;
        float acc = 0.f;
        for (int f = 0; f < 24; ++f) {
            float Sy = yst[f][0], rY0 = yst[f][1], rY63 = yst[f][2], cY0 = yst[f][3], cY63 = yst[f][4];
            float yc00 = yst[f][5], yc0W = yst[f][6], ycH0 = yst[f][7], ycHW = yst[f][8];
#pragma unroll
            for (int p = 0; p < 3; ++p)
#pragma unroll
                for (int q = 0; q < 3; ++q) {
                    float t = Sy;
                    if (p == 0) t -= rY63;
                    if (p == 2) t -= rY0;
                    if (q == 0) t -= cY63;
                    if (q == 2) t -= cY0;
                    if (p == 0 && q == 0) t += ycHW;
                    if (p == 0 && q == 2) t += ycH0;
                    if (p == 2 && q == 0) t += yc0W;
                    if (p == 2 && q == 2) t += yc00;
                    acc += w2[(((p * 3 + q) * 24 + f) * 24) + g] * t;
                }
        }
        feat[(size_t)n * 24 + g] = b2[g] + acc * (1.f / 4096.f);
    }
}

// ---------------------------------------------------------------------------
// Kernel 2: input-part of gate preactivations (embarrassingly parallel).
// G[(t*8+b)*512 + g*128 + u] = bias_g[u] + feat[b*T+t, :24] @ W_g[0:24, u]
// ---------------------------------------------------------------------------
__global__ void gpre_kernel(const float* __restrict__ feat,
                            const float* __restrict__ Wf, const float* __restrict__ bf,
                            const float* __restrict__ Wi, const float* __restrict__ bi,
                            const float* __restrict__ Wc, const float* __restrict__ bc,
                            const float* __restrict__ Wo, const float* __restrict__ bo,
                            float* __restrict__ G) {
    int blk = blockIdx.x;                     // t*8 + b
    int t = blk >> 3, b = blk & 7;
    int tid = threadIdx.x;                    // g*128 + u
    int g = tid >> 7, u = tid & 127;
    const float* W    = (g == 0) ? Wf : (g == 1) ? Wi : (g == 2) ? Wc : Wo;
    const float* bias = (g == 0) ? bf : (g == 1) ? bi : (g == 2) ? bc : bo;
    int n = b * Tt + t;
    float acc = bias[u];
#pragma unroll
    for (int k = 0; k < Ff; ++k) acc += feat[(size_t)n * Ff + k] * W[k * Uu + u];
    G[(size_t)blk * 512 + tid] = acc;
}

// ---------------------------------------------------------------------------
// Kernel 3: LSTM recurrence. One block per batch element, 1024 threads.
// Weight residency is enforced by construction this round: 32 INDIVIDUALLY
// NAMED v2f values (no arrays -> guaranteed SSA, nothing for SROA to choke
// on; rounds 1-4 all lost to arrays being demoted to scratch) under a
// 128-VGPR cap (1024 threads, 4 waves/SIMD). ~100 VGPR estimated pressure.
// Thread (up = tid&63, g = (tid>>6)&3, q = tid>>8):
//   phase A: acc(v2f) = sum_{r<32} W_g[24+32q+r][2up..2up+1] * h[32q+r]
//            (h via broadcast ds_read_b64 + pk_fma op_sel splat)
//   phase B (tid<128): sum 4 chunk partials/gate + G, activations, c/h update.
// 2 barriers per step.
// ---------------------------------------------------------------------------
__global__ __launch_bounds__(1024, 4) void lstm_kernel(
        const float* __restrict__ G,
        const float* __restrict__ Wf, const float* __restrict__ Wi,
        const float* __restrict__ Wc, const float* __restrict__ Wo,
        const float* __restrict__ out_w, const float* __restrict__ out_b,
        float* __restrict__ out) {
    int b   = blockIdx.x;
    int tid = threadIdx.x;
    int up  = tid & 63;                       // unit pair
    int g   = (tid >> 6) & 3;                 // gate (wave-uniform)
    int q   = tid >> 8;                       // row chunk (wave-uniform)
    const float* Wg = (g == 0) ? Wf : (g == 1) ? Wi : (g == 2) ? Wc : Wo;

    // 64 VGPRs of recurrent weights as NAMED SSA values (no array!).
    const float* wbase = Wg + (size_t)(Ff + 32 * q) * Uu + 2 * up;
#define LDW(i) v2f w##i = *(const v2f*)(wbase + (size_t)(i) * Uu)
    LDW(0);  LDW(1);  LDW(2);  LDW(3);  LDW(4);  LDW(5);  LDW(6);  LDW(7);
    LDW(8);  LDW(9);  LDW(10); LDW(11); LDW(12); LDW(13); LDW(14); LDW(15);
    LDW(16); LDW(17); LDW(18); LDW(19); LDW(20); LDW(21); LDW(22); LDW(23);
    LDW(24); LDW(25); LDW(26); LDW(27); LDW(28); LDW(29); LDW(30); LDW(31);
#undef LDW

    __shared__ float hs[Uu];
    __shared__ float part[16][Uu];            // [q*4+g][u]
    __shared__ float hist[Tt][Uu];

    float cs = 0.f;
    if (tid < Uu) hs[tid] = 0.f;
    __syncthreads();

    for (int t = 0; t < Tt; ++t) {
        // Prefetch this step's input-projection values (used in phase B).
        float g0 = 0.f, g1 = 0.f, g2 = 0.f, g3 = 0.f;
        if (tid < Uu) {
            const float* Gt = G + ((size_t)(t * Bb + b)) * 512 + tid;
            g0 = Gt[0]; g1 = Gt[128]; g2 = Gt[256]; g3 = Gt[384];
        }

        // phase A: 16 broadcast ds_read_b64 + 32 pk_fma (2 indep chains).
        v2f ae = {0.f, 0.f}, ao = {0.f, 0.f};
        const v2f* hp = (const v2f*)(hs + q * 32);
        // even row 2j: splat h2.lo (op_sel_hi[1]=0); odd row: splat h2.hi.
#define FMA2(j, we, wo_) { v2f h2 = hp[j]; \
        asm("v_pk_fma_f32 %0, %1, %2, %0 op_sel:[0,0,0] op_sel_hi:[1,0,1]" \
            : "+v"(ae) : "v"(we), "v"(h2)); \
        asm("v_pk_fma_f32 %0, %1, %2, %0 op_sel:[0,1,0] op_sel_hi:[1,1,1]" \
            : "+v"(ao) : "v"(wo_), "v"(h2)); }
        FMA2(0,  w0,  w1);  FMA2(1,  w2,  w3);
        FMA2(2,  w4,  w5);  FMA2(3,  w6,  w7);
        FMA2(4,  w8,  w9);  FMA2(5,  w10, w11);
        FMA2(6,  w12, w13); FMA2(7,  w14, w15);
        FMA2(8,  w16, w17); FMA2(9,  w18, w19);
        FMA2(10, w20, w21); FMA2(11, w22, w23);
        FMA2(12, w24, w25); FMA2(13, w26, w27);
        FMA2(14, w28, w29); FMA2(15, w30, w31);
#undef FMA2
        v2f acc = ae + ao;
        *(v2f*)&part[q * 4 + g][2 * up] = acc;
        __syncthreads();

        // phase B: state update on 128 threads.
        if (tid < Uu) {
            int u = tid;
            float sf = part[0][u] + part[4][u] + part[8][u]  + part[12][u] + g0;
            float si = part[1][u] + part[5][u] + part[9][u]  + part[13][u] + g1;
            float sg = part[2][u] + part[6][u] + part[10][u] + part[14][u] + g2;
            float so = part[3][u] + part[7][u] + part[11][u] + part[15][u] + g3;
            float f  = fast_sigmoid(sf);
            float i  = fast_sigmoid(si);
            float gg = fast_tanh(sg);
            float o  = fast_sigmoid(so);
            cs = cs * f + i * gg;
            float hn = fast_tanh(cs) * o;
            hs[u] = hn;
            hist[t][u] = hn;
        }
        __syncthreads();
    }

    // Epilogue: out[b][t] = hist[t] . out_w + out_b, 32 threads per t.
    int tt = tid >> 5, j = tid & 31;
    const float4* hh = (const float4*)(&hist[tt][j * 4]);
    float4 a0 = hh[0];
    const float* owp = out_w + j * 4;
    float pw = a0.x * owp[0] + a0.y * owp[1] + a0.z * owp[2] + a0.w * owp[3];
#pragma unroll
    for (int off = 16; off > 0; off >>= 1) pw += __shfl_down(pw, off, 32);
    if (j == 0) out[b * Tt + tt] = pw + out_b[0];
}

// ---------------------------------------------------------------------------
extern "C" void kernel_launch(void* const* d_in, const int* in_sizes, int n_in,
                              void* d_out, int out_size, void* d_ws, size_t ws_size,
                              hipStream_t stream) {
    const float* x   = (const float*)d_in[0];
    const float* w1  = (const float*)d_in[1];
    const float* b1  = (const float*)d_in[2];
    const float* w2  = (const float*)d_in[3];
    const float* b2  = (const float*)d_in[4];
    const float* Wf  = (const float*)d_in[5];
    const float* bf  = (const float*)d_in[6];
    const float* Wi  = (const float*)d_in[7];
    const float* bi  = (const float*)d_in[8];
    const float* Wc  = (const float*)d_in[9];
    const float* bc  = (const float*)d_in[10];
    const float* Wo  = (const float*)d_in[11];
    const float* bo  = (const float*)d_in[12];
    const float* ow  = (const float*)d_in[13];
    const float* ob  = (const float*)d_in[14];
    float* out = (float*)d_out;

    float* ws   = (float*)d_ws;
    float* feat = ws;                         // 256*24  = 6144 floats
    float* G    = ws + 6144;                  // 256*512 = 131072 floats

    convfeat_kernel<<<Bb * Tt, 256, 0, stream>>>(x, w1, b1, w2, b2, feat);
    gpre_kernel<<<Bb * Tt, 512, 0, stream>>>(feat, Wf, bf, Wi, bi, Wc, bc, Wo, bo, G);
    lstm_kernel<<<Bb, 1024, 0, stream>>>(G, Wf, Wi, Wc, Wo, ow, ob, out);
}